// Round 6
// baseline (263.375 us; speedup 1.0000x reference)
//
#include <hip/hip_runtime.h>

#define B_   2
#define H_   16
#define G_   4
#define S_   2048
#define D_   128
#define I_   2048

#define BM   128
#define BN   64
#define TPB  256   // 4 waves
#define NIT  (I_ / BN)   // 32

// T2 XOR-swizzle: permute 8-elem (16B) groups within a row by row&7.
// Applied identically on write and read (both sides are register-staged).
#define KIDX(r,c) ((r)*128 + ((c) ^ (((r)&7)<<3)))   // Ks/Us: [64][128] f16, no pad
#define VIDX(d,c) ((d)*64  + ((c) ^ (((d)&7)<<3)))   // Vt:    [128][64] f16, no pad

static constexpr float SCALE = 0.08838834764831845f;  // 1/sqrt(128)

typedef __fp16   p2v __attribute__((ext_vector_type(2)));   // cvt_pkrtz result type
typedef _Float16 h4v __attribute__((ext_vector_type(4)));
typedef _Float16 h8v __attribute__((ext_vector_type(8)));
typedef float    f4v __attribute__((ext_vector_type(4)));

__global__ __launch_bounds__(TPB, 2) void flashmlp_kernel(
    const float* __restrict__ Qg, const float* __restrict__ Kg,
    const float* __restrict__ Ug, const float* __restrict__ Vg,
    float* __restrict__ Og)
{
    // LDS: (2*64*128 + 128*64) f16 = 24576 f16 = 49152 B (2 blocks/CU easily)
    __shared__ _Float16 Ks[BN * 128];
    __shared__ _Float16 Us[BN * 128];
    __shared__ _Float16 Vt[D_ * 64];    // Vt[d][i] (transposed V tile), swizzled

    // ---- block decode with XCD swizzle: xcd = bid&7 -> kv-head = xcd>>1
    const int bid   = blockIdx.x;
    const int xcd   = bid & 7;
    const int kh    = xcd >> 1;
    const int j     = ((bid >> 3) << 1) | (xcd & 1);   // 0..127 within head
    const int stile = j & 15;
    const int bg    = j >> 4;          // 0..7
    const int b     = bg >> 2;
    const int g     = bg & 3;
    const int h     = kh * G_ + g;

    const int tid  = threadIdx.x;
    const int wave = tid >> 6;
    const int lane = tid & 63;
    const int m16  = lane & 15;
    const int qq   = lane >> 4;        // 0..3

    const size_t qbase  = ((size_t)(b * H_ + h) * S_ + (size_t)stile * BM) * D_;
    const size_t kvbase = (size_t)kh * I_ * D_;

    // ---- Q fragments, f32 -> f16 with SCALE folded in. Used as the B-operand of the
    // swapped QK^T (A/B fragment layouts are mutual transposes, so content unchanged).
    h8v qf[2][4];
#pragma unroll
    for (int qt = 0; qt < 2; ++qt) {
        const float* qp = Qg + qbase + (size_t)(wave * 32 + qt * 16 + m16) * D_;
#pragma unroll
        for (int ks = 0; ks < 4; ++ks) {
            const float4 a = *(const float4*)(qp + ks * 32 + qq * 8);
            const float4 c = *(const float4*)(qp + ks * 32 + qq * 8 + 4);
            h8v v;
            p2v* v2 = (p2v*)&v;
            v2[0] = __builtin_amdgcn_cvt_pkrtz(a.x * SCALE, a.y * SCALE);
            v2[1] = __builtin_amdgcn_cvt_pkrtz(a.z * SCALE, a.w * SCALE);
            v2[2] = __builtin_amdgcn_cvt_pkrtz(c.x * SCALE, c.y * SCALE);
            v2[3] = __builtin_amdgcn_cvt_pkrtz(c.z * SCALE, c.w * SCALE);
            qf[qt][ks] = v;
        }
    }

    // acc_o[qt][dt]: O^T tile — lane(m16,qq) reg r = O[d = dt*16+qq*4+r][q = qt*16+m16]
    f4v acc_o[2][8];
#pragma unroll
    for (int qt = 0; qt < 2; ++qt)
#pragma unroll
        for (int dt = 0; dt < 8; ++dt)
            acc_o[qt][dt] = f4v{0.f, 0.f, 0.f, 0.f};

    const int sr = tid >> 2;          // K/U staging row 0..63
    const int sc = (tid & 3) * 32;    // K/U staging col base
    const float* kbp = Kg + kvbase + (size_t)sr * D_ + sc;
    const float* ubp = Ug + kvbase + (size_t)sr * D_ + sc;

    // ---- T14 async-stage: K/U tile t+1 prefetched into regs during compute of t.
    float4 kpre[8], upre[8];
#pragma unroll
    for (int g8 = 0; g8 < 8; ++g8) {
        kpre[g8] = *(const float4*)(kbp + g8 * 4);
        upre[g8] = *(const float4*)(ubp + g8 * 4);
    }

    for (int it = 0; it < NIT; ++it) {
        const int i0 = it * BN;

        __syncthreads();  // previous iter's Ks/Us/Vt reads must complete before overwrite

        // ---- V loads for THIS tile: issue first so their latency hides under the
        // K/U cvt+ds_write work below. Thread owns (d, io): 8 i-elems of one d row.
        float vtmp[4][8];
#pragma unroll
        for (int p = 0; p < 4; ++p) {
            const int idx = p * TPB + tid;
            const int d   = idx & 127;
            const int io  = idx >> 7;   // 0..7
            const float* vp = Vg + kvbase + (size_t)(i0 + io * 8) * D_ + d;
#pragma unroll
            for (int jj = 0; jj < 8; ++jj)
                vtmp[p][jj] = vp[(size_t)jj * D_];
        }

        // ---- K/U: packed cvt + swizzled LDS write from the prefetched registers
        {
            h8v kb[4], ub[4];
            p2v* kb2 = (p2v*)kb;
            p2v* ub2 = (p2v*)ub;
#pragma unroll
            for (int g8 = 0; g8 < 8; ++g8) {
                kb2[2 * g8 + 0] = __builtin_amdgcn_cvt_pkrtz(kpre[g8].x, kpre[g8].y);
                kb2[2 * g8 + 1] = __builtin_amdgcn_cvt_pkrtz(kpre[g8].z, kpre[g8].w);
                ub2[2 * g8 + 0] = __builtin_amdgcn_cvt_pkrtz(upre[g8].x, upre[g8].y);
                ub2[2 * g8 + 1] = __builtin_amdgcn_cvt_pkrtz(upre[g8].z, upre[g8].w);
            }
#pragma unroll
            for (int w8 = 0; w8 < 4; ++w8) {
                *(h8v*)(&Ks[KIDX(sr, sc + w8 * 8)]) = kb[w8];
                *(h8v*)(&Us[KIDX(sr, sc + w8 * 8)]) = ub[w8];
            }
        }

        // ---- V: packed cvt + swizzled transposed write (one 16B chunk per thread per p)
#pragma unroll
        for (int p = 0; p < 4; ++p) {
            const int idx = p * TPB + tid;
            const int d   = idx & 127;
            const int io  = idx >> 7;
            h8v w;
            p2v* w2 = (p2v*)&w;
            w2[0] = __builtin_amdgcn_cvt_pkrtz(vtmp[p][0], vtmp[p][1]);
            w2[1] = __builtin_amdgcn_cvt_pkrtz(vtmp[p][2], vtmp[p][3]);
            w2[2] = __builtin_amdgcn_cvt_pkrtz(vtmp[p][4], vtmp[p][5]);
            w2[3] = __builtin_amdgcn_cvt_pkrtz(vtmp[p][6], vtmp[p][7]);
            *(h8v*)(&Vt[VIDX(d, io * 8)]) = w;
        }

        __syncthreads();

        // ---- issue K/U prefetch for tile t+1; completes during the MFMA phase.
        if (it + 1 < NIT) {
            const float* kp = kbp + (size_t)(it + 1) * BN * D_;
            const float* up = ubp + (size_t)(it + 1) * BN * D_;
#pragma unroll
            for (int g8 = 0; g8 < 8; ++g8) {
                kpre[g8] = *(const float4*)(kp + g8 * 4);
                upre[g8] = *(const float4*)(up + g8 * 4);
            }
        }

        // ---- per 16-i tile ct: swapped QK^T (acc = M^T[i][q]), gate in-register,
        // then PV via 16x16x16 MFMA whose B-operand layout == gated acc layout.
#pragma unroll
        for (int ct = 0; ct < 4; ++ct) {
            f4v am[2], an[2];
            am[0] = f4v{0.f, 0.f, 0.f, 0.f}; am[1] = am[0];
            an[0] = am[0]; an[1] = am[0];
            __builtin_amdgcn_s_setprio(1);
#pragma unroll
            for (int ks = 0; ks < 4; ++ks) {
                const h8v kf = *(const h8v*)(&Ks[KIDX(ct * 16 + m16, ks * 32 + qq * 8)]);
                const h8v uf = *(const h8v*)(&Us[KIDX(ct * 16 + m16, ks * 32 + qq * 8)]);
                am[0] = __builtin_amdgcn_mfma_f32_16x16x32_f16(kf, qf[0][ks], am[0], 0, 0, 0);
                am[1] = __builtin_amdgcn_mfma_f32_16x16x32_f16(kf, qf[1][ks], am[1], 0, 0, 0);
                an[0] = __builtin_amdgcn_mfma_f32_16x16x32_f16(uf, qf[0][ks], an[0], 0, 0, 0);
                an[1] = __builtin_amdgcn_mfma_f32_16x16x32_f16(uf, qf[1][ks], an[1], 0, 0, 0);
            }
            __builtin_amdgcn_s_setprio(0);

            // gate: A = silu(M) * N (SCALE folded into Q); pack straight into the
            // 16x16x16 B-operand fragment (lane holds k = qq*4+j, col = m16).
            h4v pb[2];
#pragma unroll
            for (int qt = 0; qt < 2; ++qt) {
                p2v* pp = (p2v*)&pb[qt];
#pragma unroll
                for (int pr = 0; pr < 2; ++pr) {
                    const float m0 = am[qt][2 * pr + 0], n0 = an[qt][2 * pr + 0];
                    const float m1 = am[qt][2 * pr + 1], n1 = an[qt][2 * pr + 1];
                    const float g0 = m0 * __builtin_amdgcn_rcpf(1.f + __expf(-m0)) * n0;
                    const float g1 = m1 * __builtin_amdgcn_rcpf(1.f + __expf(-m1)) * n1;
                    pp[pr] = __builtin_amdgcn_cvt_pkrtz(g0, g1);
                }
            }

            // PV: O^T[d][q] += Vt-frag * pb.  A-op: lane(row=d-local=m16, k=qq*4+j).
            h4v va[8];
#pragma unroll
            for (int dt = 0; dt < 8; ++dt)
                va[dt] = *(const h4v*)(&Vt[VIDX(dt * 16 + m16, ct * 16 + qq * 4)]);
            __builtin_amdgcn_s_setprio(1);
#pragma unroll
            for (int dt = 0; dt < 8; ++dt) {
                acc_o[0][dt] = __builtin_amdgcn_mfma_f32_16x16x16f16(va[dt], pb[0], acc_o[0][dt], 0, 0, 0);
                acc_o[1][dt] = __builtin_amdgcn_mfma_f32_16x16x16f16(va[dt], pb[1], acc_o[1][dt], 0, 0, 0);
            }
            __builtin_amdgcn_s_setprio(0);
        }
    }

    // ---- epilogue: O^T acc -> global fp32, native float4 stores (reg axis = d)
#pragma unroll
    for (int qt = 0; qt < 2; ++qt) {
        const int row = stile * BM + wave * 32 + qt * 16 + m16;
        float* op = Og + ((size_t)(b * H_ + h) * S_ + row) * D_;
#pragma unroll
        for (int dt = 0; dt < 8; ++dt)
            *(f4v*)(op + dt * 16 + qq * 4) = acc_o[qt][dt];
    }
}

extern "C" void kernel_launch(void* const* d_in, const int* in_sizes, int n_in,
                              void* d_out, int out_size, void* d_ws, size_t ws_size,
                              hipStream_t stream) {
    const float* Q = (const float*)d_in[0];
    const float* K = (const float*)d_in[1];
    const float* U = (const float*)d_in[2];
    const float* V = (const float*)d_in[3];
    float* out = (float*)d_out;

    const int grid = (S_ / BM) * B_ * H_;   // 512 blocks, all co-resident at 2/CU
    flashmlp_kernel<<<dim3(grid), dim3(TPB), 0, stream>>>(Q, K, U, V, out);
}